// Round 1
// baseline (459.399 us; speedup 1.0000x reference)
//
#include <hip/hip_runtime.h>
#include <stdint.h>

typedef __attribute__((ext_vector_type(4))) float f32x4;
typedef __attribute__((ext_vector_type(8))) short bf16x8;
typedef __attribute__((ext_vector_type(8))) unsigned short u16x8;

#define NPIX 100352      // 32*56*56
#define CDIM 256
#define QKVN 768
#define BATCH 32
#define HWDIM 56

__device__ __forceinline__ unsigned short f2bf(float f) {
  union { float f; unsigned int u; } cv; cv.f = f;
  unsigned int u = cv.u;
  unsigned int r = (u + 0x7FFFu + ((u >> 16) & 1u)) >> 16;
  return (unsigned short)r;
}
__device__ __forceinline__ float bf2f(unsigned short h) {
  union { unsigned int u; float f; } cv; cv.u = ((unsigned int)h) << 16;
  return cv.f;
}

// ---------------- fp32 -> bf16 convert (8 elems/thread) ----------------
__global__ __launch_bounds__(256) void cvt_kernel(const float* __restrict__ in,
                                                  unsigned short* __restrict__ out,
                                                  int n8) {
  int i = blockIdx.x * 256 + threadIdx.x;
  if (i >= n8) return;
  const float4* p = reinterpret_cast<const float4*>(in) + (size_t)i * 2;
  float4 a = p[0], b = p[1];
  u16x8 r;
  r[0] = f2bf(a.x); r[1] = f2bf(a.y); r[2] = f2bf(a.z); r[3] = f2bf(a.w);
  r[4] = f2bf(b.x); r[5] = f2bf(b.y); r[6] = f2bf(b.z); r[7] = f2bf(b.w);
  *(reinterpret_cast<u16x8*>(out) + i) = r;
}

// ---------------- bf16 MFMA GEMM: C[M,N] = A[M,K] * Bt[N,K]^T + bias ----------------
__device__ __forceinline__ void gload16(const unsigned short* g, unsigned short* l) {
  __builtin_amdgcn_global_load_lds((const __attribute__((address_space(1))) void*)g,
                                   (__attribute__((address_space(3))) void*)l, 16, 0, 0);
}

template<bool OUT_BF16>
__global__ __launch_bounds__(256) void gemm_kernel(
    const unsigned short* __restrict__ A,
    const unsigned short* __restrict__ Bt,
    const float* __restrict__ bias,
    void* __restrict__ out,
    int M, int N, int K)
{
  __shared__ unsigned short As[2][128 * 32];
  __shared__ unsigned short Bs[2][128 * 32];
  const int t = threadIdx.x;
  const int lane = t & 63;
  const int wave = t >> 6;
  const int wr = wave >> 1, wc = wave & 1;
  const long m0 = (long)blockIdx.x * 128;
  const long n0 = (long)blockIdx.y * 128;
  const int nsteps = K >> 5;
  const int r0 = lane & 15;
  const int kh = lane >> 4;

  f32x4 acc[4][4] = {};

  const unsigned short* gA = A + m0 * K;
  const unsigned short* gB = Bt + n0 * K;

  // stage k-step 0 into buffer 0
  {
    #pragma unroll
    for (int j = 0; j < 2; ++j) {
      int c = t + 256 * j;
      int row = c >> 2, ko = (c & 3) << 3;
      gload16(gA + (size_t)row * K + ko, &As[0][c * 8]);
      gload16(gB + (size_t)row * K + ko, &Bs[0][c * 8]);
    }
  }
  __syncthreads();  // drains vmcnt before first reads

  for (int s = 0; s < nsteps; ++s) {
    int cur = s & 1;
    if (s + 1 < nsteps) {
      const unsigned short* gA2 = gA + (s + 1) * 32;
      const unsigned short* gB2 = gB + (s + 1) * 32;
      #pragma unroll
      for (int j = 0; j < 2; ++j) {
        int c = t + 256 * j;
        int row = c >> 2, ko = (c & 3) << 3;
        gload16(gA2 + (size_t)row * K + ko, &As[cur ^ 1][c * 8]);
        gload16(gB2 + (size_t)row * K + ko, &Bs[cur ^ 1][c * 8]);
      }
    }
    bf16x8 af[4], bfr[4];
    #pragma unroll
    for (int mf = 0; mf < 4; ++mf)
      af[mf] = *reinterpret_cast<const bf16x8*>(&As[cur][(wr * 64 + mf * 16 + r0) * 32 + kh * 8]);
    #pragma unroll
    for (int nf = 0; nf < 4; ++nf)
      bfr[nf] = *reinterpret_cast<const bf16x8*>(&Bs[cur][(wc * 64 + nf * 16 + r0) * 32 + kh * 8]);
    #pragma unroll
    for (int mf = 0; mf < 4; ++mf) {
      #pragma unroll
      for (int nf = 0; nf < 4; ++nf)
        acc[mf][nf] = __builtin_amdgcn_mfma_f32_16x16x32_bf16(af[mf], bfr[nf], acc[mf][nf], 0, 0, 0);
    }
    __syncthreads();
  }

  // epilogue: D layout col = lane&15, row = (lane>>4)*4 + reg
  #pragma unroll
  for (int mf = 0; mf < 4; ++mf) {
    #pragma unroll
    for (int nf = 0; nf < 4; ++nf) {
      long col = n0 + wc * 64 + nf * 16 + r0;
      float bv = bias[col];
      #pragma unroll
      for (int r = 0; r < 4; ++r) {
        long row = m0 + wr * 64 + mf * 16 + kh * 4 + r;
        float v = acc[mf][nf][r] + bv;
        if (OUT_BF16) ((unsigned short*)out)[row * N + col] = f2bf(v);
        else          ((float*)out)[row * N + col] = v;
      }
    }
  }
}

// ---------------- shifted-window attention core ----------------
// one block = (window, head); 64 threads
__global__ __launch_bounds__(64) void attn_kernel(
    const unsigned short* __restrict__ qkv,   // [NPIX][768] bf16, pixel order
    const float* __restrict__ table,          // [169][8]
    unsigned short* __restrict__ aout)        // [NPIX][256] bf16, pixel order
{
  const int head = blockIdx.x & 7;
  const int win = blockIdx.x >> 3;
  const int b = win >> 6;
  const int gi = (win >> 3) & 7;
  const int gj = win & 7;
  const int t = threadIdx.x;

  __shared__ float Ks[49][32];
  __shared__ float Vs[49][32];
  __shared__ float S[49][53];
  __shared__ float rinv[49];
  __shared__ int reg_s[49];
  __shared__ int pix_s[49];

  if (t < 49) {
    int wi = t / 7, wj = t % 7;
    int hs = gi * 7 + wi, ws = gj * 7 + wj;   // shifted coords
    int ph = hs + 3; if (ph >= HWDIM) ph -= HWDIM;  // original pixel
    int pw = ws + 3; if (pw >= HWDIM) pw -= HWDIM;
    pix_s[t] = (b * HWDIM + ph) * HWDIM + pw;
    int rh = (hs < 49) ? 0 : ((hs < 53) ? 1 : 2);
    int rw = (ws < 49) ? 0 : ((ws < 53) ? 1 : 2);
    reg_s[t] = rh * 3 + rw;
  }
  __syncthreads();

  // load K and V head-slices into LDS as fp32
  #pragma unroll
  for (int j0 = 0; j0 < 64; j0 += 16) {
    int j = j0 + (t >> 2);
    if (j < 49) {
      int c = (t & 3) * 8;
      const unsigned short* kp = qkv + (size_t)pix_s[j] * QKVN + 256 + head * 32 + c;
      u16x8 kv = *reinterpret_cast<const u16x8*>(kp);
      u16x8 vv = *reinterpret_cast<const u16x8*>(kp + 256);
      #pragma unroll
      for (int e = 0; e < 8; ++e) {
        Ks[j][c + e] = bf2f(kv[e]);
        Vs[j][c + e] = bf2f(vv[e]);
      }
    }
  }
  __syncthreads();

  const float scale = 0.17677669529663687f;  // 1/sqrt(32)
  if (t < 49) {
    int i = t;
    float qv[32];
    const unsigned short* qp = qkv + (size_t)pix_s[i] * QKVN + head * 32;
    u16x8 q0 = ((const u16x8*)qp)[0];
    u16x8 q1 = ((const u16x8*)qp)[1];
    u16x8 q2 = ((const u16x8*)qp)[2];
    u16x8 q3 = ((const u16x8*)qp)[3];
    #pragma unroll
    for (int e = 0; e < 8; ++e) {
      qv[e]      = bf2f(q0[e]) * scale;
      qv[8 + e]  = bf2f(q1[e]) * scale;
      qv[16 + e] = bf2f(q2[e]) * scale;
      qv[24 + e] = bf2f(q3[e]) * scale;
    }
    int wi = i / 7, wj = i % 7;
    int ri = reg_s[i];
    float mx = -1e30f;
    for (int j = 0; j < 49; ++j) {
      float dot = 0.f;
      #pragma unroll
      for (int d = 0; d < 32; ++d) dot += qv[d] * Ks[j][d];
      int dr = wi - (j / 7) + 6;
      int dc = wj - (j % 7) + 6;
      float bias = table[(dr * 13 + dc) * 8 + head];
      float msk = (reg_s[j] == ri) ? 0.f : -100.f;
      float val = dot + bias + msk;
      S[i][j] = val;
      mx = fmaxf(mx, val);
    }
    float sum = 0.f;
    for (int j = 0; j < 49; ++j) {
      float e = __expf(S[i][j] - mx);
      S[i][j] = e;
      sum += e;
    }
    rinv[i] = 1.0f / sum;
  }
  __syncthreads();

  // PV: out[i][d] = (sum_j S[i][j]*V[j][d]) * rinv[i]
  for (int idx = t; idx < 49 * 32; idx += 64) {
    int i = idx >> 5, d = idx & 31;
    float accv = 0.f;
    for (int j = 0; j < 49; ++j) accv += S[i][j] * Vs[j][d];
    accv *= rinv[i];
    aout[(size_t)pix_s[i] * CDIM + head * 32 + d] = f2bf(accv);
  }
}

// ---------------- launch ----------------
extern "C" void kernel_launch(void* const* d_in, const int* in_sizes, int n_in,
                              void* d_out, int out_size, void* d_ws, size_t ws_size,
                              hipStream_t stream) {
  const float* x      = (const float*)d_in[0];
  const float* qkv_w  = (const float*)d_in[1];
  const float* qkv_b  = (const float*)d_in[2];
  const float* proj_w = (const float*)d_in[3];
  const float* proj_b = (const float*)d_in[4];
  const float* table  = (const float*)d_in[5];

  char* ws = (char*)d_ws;
  // layout: x_bf (51,380,224 B; reused as aout) | qkv_bf (154,140,672 B) | qkvw_bf | projw_bf
  unsigned short* x_bf    = (unsigned short*)ws;
  unsigned short* qkv_bf  = (unsigned short*)(ws + 51380224);
  unsigned short* qkvw_bf = (unsigned short*)(ws + 205520896);
  unsigned short* projw_bf= (unsigned short*)(ws + 205914112);
  unsigned short* aout    = x_bf;

  // converts
  cvt_kernel<<<12544, 256, 0, stream>>>(x, x_bf, NPIX * CDIM / 8);
  cvt_kernel<<<96, 256, 0, stream>>>(qkv_w, qkvw_bf, QKVN * CDIM / 8);
  cvt_kernel<<<32, 256, 0, stream>>>(proj_w, projw_bf, CDIM * CDIM / 8);

  // QKV GEMM: [100352,256] x [768,256]^T -> bf16 [100352,768]
  dim3 g1(NPIX / 128, QKVN / 128);
  gemm_kernel<true><<<g1, 256, 0, stream>>>(x_bf, qkvw_bf, qkv_b, qkv_bf,
                                            NPIX, QKVN, CDIM);

  // attention: 2048 windows * 8 heads
  attn_kernel<<<2048 * 8, 64, 0, stream>>>(qkv_bf, table, aout);

  // proj GEMM: [100352,256] x [256,256]^T -> f32 d_out
  dim3 g2(NPIX / 128, CDIM / 128);
  gemm_kernel<false><<<g2, 256, 0, stream>>>(aout, projw_bf, proj_b, (float*)d_out,
                                             NPIX, CDIM, CDIM);
}

// Round 2
// 234.058 us; speedup vs baseline: 1.9628x; 1.9628x over previous
//
#include <hip/hip_runtime.h>
#include <stdint.h>

typedef __attribute__((ext_vector_type(4))) float f32x4;
typedef __attribute__((ext_vector_type(8))) short bf16x8;
typedef __attribute__((ext_vector_type(8))) unsigned short u16x8;

#define NPIX 100352      // 32*56*56
#define CDIM 256
#define QKVN 768
#define HWDIM 56

__device__ __forceinline__ unsigned short f2bf(float f) {
  union { float f; unsigned int u; } cv; cv.f = f;
  unsigned int u = cv.u;
  unsigned int r = (u + 0x7FFFu + ((u >> 16) & 1u)) >> 16;
  return (unsigned short)r;
}
__device__ __forceinline__ float bf2f(unsigned short h) {
  union { unsigned int u; float f; } cv; cv.u = ((unsigned int)h) << 16;
  return cv.f;
}

// ---------------- fp32 -> bf16 convert (8 elems/thread) ----------------
__global__ __launch_bounds__(256) void cvt_kernel(const float* __restrict__ in,
                                                  unsigned short* __restrict__ out,
                                                  int n8) {
  int i = blockIdx.x * 256 + threadIdx.x;
  if (i >= n8) return;
  const float4* p = reinterpret_cast<const float4*>(in) + (size_t)i * 2;
  float4 a = p[0], b = p[1];
  u16x8 r;
  r[0] = f2bf(a.x); r[1] = f2bf(a.y); r[2] = f2bf(a.z); r[3] = f2bf(a.w);
  r[4] = f2bf(b.x); r[5] = f2bf(b.y); r[6] = f2bf(b.z); r[7] = f2bf(b.w);
  *(reinterpret_cast<u16x8*>(out) + i) = r;
}

// ---------------- bf16 MFMA GEMM: C[M,N] = A[M,K] * Bt[N,K]^T + bias ----------------
__device__ __forceinline__ void gload16(const unsigned short* g, unsigned short* l) {
  __builtin_amdgcn_global_load_lds((const __attribute__((address_space(1))) void*)g,
                                   (__attribute__((address_space(3))) void*)l, 16, 0, 0);
}

template<bool OUT_BF16>
__global__ __launch_bounds__(256) void gemm_kernel(
    const unsigned short* __restrict__ A,
    const unsigned short* __restrict__ Bt,
    const float* __restrict__ bias,
    void* __restrict__ out,
    int M, int N, int K)
{
  __shared__ unsigned short As[2][128 * 32];
  __shared__ unsigned short Bs[2][128 * 32];
  const int t = threadIdx.x;
  const int lane = t & 63;
  const int wave = t >> 6;
  const int wr = wave >> 1, wc = wave & 1;
  const long m0 = (long)blockIdx.x * 128;
  const long n0 = (long)blockIdx.y * 128;
  const int nsteps = K >> 5;
  const int r0 = lane & 15;
  const int kh = lane >> 4;

  f32x4 acc[4][4] = {};

  const unsigned short* gA = A + m0 * K;
  const unsigned short* gB = Bt + n0 * K;

  {
    #pragma unroll
    for (int j = 0; j < 2; ++j) {
      int c = t + 256 * j;
      int row = c >> 2, ko = (c & 3) << 3;
      gload16(gA + (size_t)row * K + ko, &As[0][c * 8]);
      gload16(gB + (size_t)row * K + ko, &Bs[0][c * 8]);
    }
  }
  __syncthreads();

  for (int s = 0; s < nsteps; ++s) {
    int cur = s & 1;
    if (s + 1 < nsteps) {
      const unsigned short* gA2 = gA + (s + 1) * 32;
      const unsigned short* gB2 = gB + (s + 1) * 32;
      #pragma unroll
      for (int j = 0; j < 2; ++j) {
        int c = t + 256 * j;
        int row = c >> 2, ko = (c & 3) << 3;
        gload16(gA2 + (size_t)row * K + ko, &As[cur ^ 1][c * 8]);
        gload16(gB2 + (size_t)row * K + ko, &Bs[cur ^ 1][c * 8]);
      }
    }
    bf16x8 af[4], bfr[4];
    #pragma unroll
    for (int mf = 0; mf < 4; ++mf)
      af[mf] = *reinterpret_cast<const bf16x8*>(&As[cur][(wr * 64 + mf * 16 + r0) * 32 + kh * 8]);
    #pragma unroll
    for (int nf = 0; nf < 4; ++nf)
      bfr[nf] = *reinterpret_cast<const bf16x8*>(&Bs[cur][(wc * 64 + nf * 16 + r0) * 32 + kh * 8]);
    #pragma unroll
    for (int mf = 0; mf < 4; ++mf) {
      #pragma unroll
      for (int nf = 0; nf < 4; ++nf)
        acc[mf][nf] = __builtin_amdgcn_mfma_f32_16x16x32_bf16(af[mf], bfr[nf], acc[mf][nf], 0, 0, 0);
    }
    __syncthreads();
  }

  #pragma unroll
  for (int mf = 0; mf < 4; ++mf) {
    #pragma unroll
    for (int nf = 0; nf < 4; ++nf) {
      long col = n0 + wc * 64 + nf * 16 + r0;
      float bv = bias[col];
      #pragma unroll
      for (int r = 0; r < 4; ++r) {
        long row = m0 + wr * 64 + mf * 16 + kh * 4 + r;
        float v = acc[mf][nf][r] + bv;
        if (OUT_BF16) ((unsigned short*)out)[row * N + col] = f2bf(v);
        else          ((float*)out)[row * N + col] = v;
      }
    }
  }
}

// ---------------- shifted-window attention core (MFMA) ----------------
// one block = (window, head); 64 threads = 1 wave
__global__ __launch_bounds__(64) void attn_kernel(
    const unsigned short* __restrict__ qkv,   // [NPIX][768] bf16, pixel order
    const float* __restrict__ table,          // [169][8]
    unsigned short* __restrict__ aout)        // [NPIX][256] bf16, pixel order
{
  const int head = blockIdx.x & 7;
  const int win = blockIdx.x >> 3;
  const int b = win >> 6;
  const int gi = (win >> 3) & 7;
  const int gj = win & 7;
  const int t = threadIdx.x;       // 0..63, one wave

  __shared__ unsigned short Vt[32 * 72];   // V transposed: Vt[d][j], stride 72
  __shared__ unsigned short P[64 * 72];    // probs bf16, stride 72
  __shared__ float tb_s[224];              // per-head rel-pos bias table (169 valid)
  __shared__ int pix_s[64];

  // ---- phase 1: window pixel map, zero Vt, load bias table ----
  {
    int idx = (t < 49) ? t : 48;
    int wi = idx / 7, wj = idx - (idx / 7) * 7;
    int hs = gi * 7 + wi, ws = gj * 7 + wj;
    int ph = hs + 3; if (ph >= HWDIM) ph -= HWDIM;
    int pw = ws + 3; if (pw >= HWDIM) pw -= HWDIM;
    pix_s[t] = (b * HWDIM + ph) * HWDIM + pw;
  }
  {
    f32x4 z = {};
    f32x4* vz = (f32x4*)Vt;   // 32*72*2 B = 288 f32x4
    #pragma unroll
    for (int i = 0; i < 5; ++i) { int o = t + i * 64; if (o < 288) vz[o] = z; }
  }
  for (int i = t; i < 224; i += 64) tb_s[i] = (i < 169) ? table[i * 8 + head] : 0.f;
  __syncthreads();

  const int fr = t & 15;           // fragment row/col lane part
  const int kq = (t >> 4) * 8;     // fragment k offset (elements)

  // ---- phase 2: Q/K fragments direct from global; V -> LDS transposed ----
  bf16x8 qf[4], kf[4];
  #pragma unroll
  for (int mf = 0; mf < 4; ++mf) {
    int row = mf * 16 + fr;
    int p = pix_s[(row < 49) ? row : 48];
    const unsigned short* base = qkv + (size_t)p * QKVN + head * 32 + kq;
    qf[mf] = *reinterpret_cast<const bf16x8*>(base);          // Q
    kf[mf] = *reinterpret_cast<const bf16x8*>(base + 256);    // K
  }
  {
    int c = (t & 3) * 8;
    #pragma unroll
    for (int it = 0; it < 4; ++it) {
      int j = (t >> 2) + it * 16;
      if (j < 49) {
        const u16x8 vv = *reinterpret_cast<const u16x8*>(
            qkv + (size_t)pix_s[j] * QKVN + 512 + head * 32 + c);
        #pragma unroll
        for (int e = 0; e < 8; ++e) Vt[(c + e) * 72 + j] = vv[e];
      }
    }
  }

  // ---- QK^T: 16 MFMAs (registers only, no barrier needed yet) ----
  f32x4 acc[4][4] = {};
  #pragma unroll
  for (int mf = 0; mf < 4; ++mf) {
    #pragma unroll
    for (int nf = 0; nf < 4; ++nf)
      acc[mf][nf] = __builtin_amdgcn_mfma_f32_16x16x32_bf16(qf[mf], kf[nf], acc[mf][nf], 0, 0, 0);
  }

  // ---- softmax (no max-subtract: |S| <= ~1, mask -> exp -> 0) ----
  const float scale = 0.17677669529663687f;  // 1/sqrt(32)
  int jwi[4], jwj[4], jreg[4]; bool jok[4];
  #pragma unroll
  for (int nf = 0; nf < 4; ++nf) {
    int jj = nf * 16 + fr;
    jok[nf] = jj < 49;
    jwi[nf] = jj / 7; jwj[nf] = jj - jwi[nf] * 7;
    int rh = (gi < 7) ? 0 : ((jwi[nf] < 4) ? 1 : 2);
    int rw = (gj < 7) ? 0 : ((jwj[nf] < 4) ? 1 : 2);
    jreg[nf] = rh * 3 + rw;
  }
  float rinv_l[4][4];
  #pragma unroll
  for (int mf = 0; mf < 4; ++mf) {
    #pragma unroll
    for (int r = 0; r < 4; ++r) {
      int i = mf * 16 + (t >> 4) * 4 + r;
      int iwi = i / 7, iwj = i - (i / 7) * 7;
      int irh = (gi < 7) ? 0 : ((iwi < 4) ? 1 : 2);
      int irw = (gj < 7) ? 0 : ((iwj < 4) ? 1 : 2);
      int ireg = irh * 3 + irw;
      float s = 0.f;
      float ev[4];
      #pragma unroll
      for (int nf = 0; nf < 4; ++nf) {
        int idx = (iwi - jwi[nf] + 6) * 13 + (iwj - jwj[nf] + 6);
        idx = max(0, min(idx, 223));
        float add = tb_s[idx] + ((ireg == jreg[nf]) ? 0.f : -100.f);
        float val = jok[nf] ? (acc[mf][nf][r] * scale + add) : -1e30f;
        float e = __expf(val);
        ev[nf] = e; s += e;
      }
      s += __shfl_xor(s, 1); s += __shfl_xor(s, 2);
      s += __shfl_xor(s, 4); s += __shfl_xor(s, 8);
      rinv_l[mf][r] = 1.0f / s;
      int rowoff = i * 72;
      #pragma unroll
      for (int nf = 0; nf < 4; ++nf)
        P[rowoff + nf * 16 + fr] = f2bf(ev[nf]);
    }
  }
  __syncthreads();   // P and Vt ready

  // ---- PV: 16 MFMAs ----
  f32x4 o[4][2] = {};
  #pragma unroll
  for (int ks = 0; ks < 2; ++ks) {
    bf16x8 pf[4], vf[2];
    #pragma unroll
    for (int mt = 0; mt < 4; ++mt)
      pf[mt] = *reinterpret_cast<const bf16x8*>(&P[(mt * 16 + fr) * 72 + ks * 32 + kq]);
    #pragma unroll
    for (int nt = 0; nt < 2; ++nt)
      vf[nt] = *reinterpret_cast<const bf16x8*>(&Vt[(nt * 16 + fr) * 72 + ks * 32 + kq]);
    #pragma unroll
    for (int mt = 0; mt < 4; ++mt) {
      #pragma unroll
      for (int nt = 0; nt < 2; ++nt)
        o[mt][nt] = __builtin_amdgcn_mfma_f32_16x16x32_bf16(pf[mt], vf[nt], o[mt][nt], 0, 0, 0);
    }
  }

  // ---- store (normalize by 1/rowsum here) ----
  #pragma unroll
  for (int mt = 0; mt < 4; ++mt) {
    #pragma unroll
    for (int r = 0; r < 4; ++r) {
      int i = mt * 16 + (t >> 4) * 4 + r;
      if (i < 49) {
        float rv = rinv_l[mt][r];
        unsigned short* op = aout + (size_t)pix_s[i] * CDIM + head * 32;
        op[fr]      = f2bf(o[mt][0][r] * rv);
        op[16 + fr] = f2bf(o[mt][1][r] * rv);
      }
    }
  }
}

// ---------------- launch ----------------
extern "C" void kernel_launch(void* const* d_in, const int* in_sizes, int n_in,
                              void* d_out, int out_size, void* d_ws, size_t ws_size,
                              hipStream_t stream) {
  const float* x      = (const float*)d_in[0];
  const float* qkv_w  = (const float*)d_in[1];
  const float* qkv_b  = (const float*)d_in[2];
  const float* proj_w = (const float*)d_in[3];
  const float* proj_b = (const float*)d_in[4];
  const float* table  = (const float*)d_in[5];

  char* ws = (char*)d_ws;
  unsigned short* x_bf    = (unsigned short*)ws;
  unsigned short* qkv_bf  = (unsigned short*)(ws + 51380224);
  unsigned short* qkvw_bf = (unsigned short*)(ws + 205520896);
  unsigned short* projw_bf= (unsigned short*)(ws + 205914112);
  unsigned short* aout    = x_bf;

  cvt_kernel<<<12544, 256, 0, stream>>>(x, x_bf, NPIX * CDIM / 8);
  cvt_kernel<<<96, 256, 0, stream>>>(qkv_w, qkvw_bf, QKVN * CDIM / 8);
  cvt_kernel<<<32, 256, 0, stream>>>(proj_w, projw_bf, CDIM * CDIM / 8);

  dim3 g1(NPIX / 128, QKVN / 128);
  gemm_kernel<true><<<g1, 256, 0, stream>>>(x_bf, qkvw_bf, qkv_b, qkv_bf,
                                            NPIX, QKVN, CDIM);

  attn_kernel<<<2048 * 8, 64, 0, stream>>>(qkv_bf, table, aout);

  dim3 g2(NPIX / 128, CDIM / 128);
  gemm_kernel<false><<<g2, 256, 0, stream>>>(aout, projw_bf, proj_b, (float*)d_out,
                                             NPIX, CDIM, CDIM);
}